// Round 16
// baseline (39.328 us; speedup 1.0000x reference)
//
#include <hip/hip_runtime.h>

// InstanceRouteOptimizationArea — RUDY map via impulse/cumsum trick.
// Round 16: finer windows + smaller partials.
// R14 decode: accum occupancy 53.7% at one full residency generation =>
// straggler tail (edge windows ~2x hits, y-Beta skew). R15 ledger: accum~20,
// PT traffic 16MB w + 16MB r. Fix: NW=4/NWIN=64/NCHUNK=16 (grid still 1024,
// chunk low-bits -> same-XCD L2 slices): PT halves to 8MB, finer window
// quantum + larger fixed-filter share shrink relative tail. wmask -> u64.

#define NB 256
#define NW 4           // rows per window
#define NWIN 64        // NB/NW
#define NCHUNK 16      // grid K2 = NWIN*NCHUNK = 1024
#define K2_THREADS 512
#define FXS 65536.0f
#define INV_FXS (1.0f / 65536.0f)
#define LCAP 1000      // LDS list capacity
#define LFLUSH 488     // flush threshold

__device__ __forceinline__ long long load_idx(const void* p, long long i, int is64) {
    if (is64) return ((const long long*)p)[i];
    return (long long)((const int*)p)[i];
}

// ---------------- K1: per-net bbox + wmask(u64)/yb/rd ----------------
__global__ void bbox_kernel(const float* __restrict__ pin_pos,
                            const float* __restrict__ net_weights,
                            const void* __restrict__ netpin_start,
                            const void* __restrict__ flat_netpin,
                            unsigned long long* __restrict__ wmask,
                            float2* __restrict__ yb,
                            float4* __restrict__ rd,
                            int num_nets, int num_pins) {
    int gid = blockIdx.x * blockDim.x + threadIdx.x;
    int n = gid >> 2, k = gid & 3;
    if (n >= num_nets) return;
    const int is64 = (((const int*)netpin_start)[1] == 0);
    long long s = load_idx(netpin_start, n, is64);
    long long e = load_idx(netpin_start, n + 1, is64);
    float xmn = 3e38f, xmx = -3e38f, ymn = 3e38f, ymx = -3e38f;
    if (e - s == 4) {
        long long pin = load_idx(flat_netpin, s + k, is64);
        float px = pin_pos[pin], py = pin_pos[pin + num_pins];
        xmn = px; xmx = px; ymn = py; ymx = py;
    } else if (k == 0) {
        for (long long p = s; p < e; ++p) {
            long long pin = load_idx(flat_netpin, p, is64);
            float px = pin_pos[pin], py = pin_pos[pin + num_pins];
            xmn = fminf(xmn, px); xmx = fmaxf(xmx, px);
            ymn = fminf(ymn, py); ymx = fmaxf(ymx, py);
        }
    }
    #pragma unroll
    for (int m = 1; m <= 2; m <<= 1) {
        xmn = fminf(xmn, __shfl_xor(xmn, m));
        xmx = fmaxf(xmx, __shfl_xor(xmx, m));
        ymn = fminf(ymn, __shfl_xor(ymn, m));
        ymx = fmaxf(ymx, __shfl_xor(ymx, m));
    }
    if (k) return;
    if (e <= s) { wmask[n] = 0ull; return; }
    float wx = xmx - xmn, wy = ymx - ymn;
    float area = fmaxf(wx * wy, 1e-6f);
    float w = net_weights[n];
    const float INVB = 1.0f / 3.90625f;
    int j0 = (int)floorf(ymn * INVB);
    int j1 = (int)floorf(ymx * INVB);
    unsigned long long m = 0ull;
    if ((unsigned)j0 < 256u)       m |= 1ull << (j0 >> 2);
    if ((unsigned)(j0 + 1) < 256u) m |= 1ull << ((j0 + 1) >> 2);
    if ((unsigned)j1 < 256u)       m |= 1ull << (j1 >> 2);
    if ((unsigned)(j1 + 1) < 256u) m |= 1ull << ((j1 + 1) >> 2);
    wmask[n] = m;
    yb[n] = make_float2(ymn, ymx);
    rd[n] = make_float4(xmn, xmx, w * wx / area, w * wy / area);
}

// -- K2: ballot-compacted splat + i32 LDS atomics + x-cumsum + PT store --
__global__ __launch_bounds__(K2_THREADS) void accum8(
        const unsigned long long* __restrict__ wmask,
        const float2* __restrict__ yb,
        const float4* __restrict__ rd,
        float* __restrict__ PT,          // [NCHUNK][2][NB(x)][NB(y)]
        int num_nets) {
    __shared__ float acc[2 * NW * NB];   // 8 KiB
    __shared__ float l_y0[LCAP], l_y1[LCAP], l_x0[LCAP], l_x1[LCAP];
    __shared__ float l_dh[LCAP], l_dv[LCAP];
    __shared__ int   lcount;
    int* acci = (int*)acc;
    const int win   = blockIdx.x >> 4;   // 0..63
    const int chunk = blockIdx.x & 15;   // 0..15 (stride-16 blocks share XCD)
    const int r0    = win * NW;
    const int tid   = threadIdx.x;
    const int lane  = tid & 63;
    const float BSX  = 3.90625f;
    const float INVB = 1.0f / 3.90625f;

    for (int i = tid; i < 2 * NW * NB; i += K2_THREADS) acci[i] = 0;
    if (tid == 0) lcount = 0;
    __syncthreads();

    const int c0 = (int)((long long)num_nets * chunk / NCHUNK);
    const int c1 = (int)((long long)num_nets * (chunk + 1) / NCHUNK);
    const int nstrips = (c1 - c0 + K2_THREADS - 1) / K2_THREADS;

    for (int s = 0; s < nstrips; ++s) {
        int n = c0 + s * K2_THREADS + tid;
        bool hit = (n < c1) && ((wmask[n] >> win) & 1ull);
        float2 y; float4 r;
        if (hit) { y = yb[n]; r = rd[n]; }
        unsigned long long m = __ballot(hit);
        if (m) {
            int base = 0;
            if (lane == 0) base = atomicAdd(&lcount, (int)__popcll(m));
            base = __shfl(base, 0);
            if (hit) {
                int pos = base + (int)__popcll(m & ((1ull << lane) - 1ull));
                l_y0[pos] = y.x; l_y1[pos] = y.y;
                l_x0[pos] = r.x; l_x1[pos] = r.y;
                l_dh[pos] = r.z; l_dv[pos] = r.w;
            }
        }
        __syncthreads();
        int cnt = lcount;                       // uniform after barrier
        if (cnt >= LFLUSH || s == nstrips - 1) {
            for (int i = tid; i < cnt; i += K2_THREADS) {
                float ty0 = l_y0[i] * INVB, fj0 = floorf(ty0);
                float ty1 = l_y1[i] * INVB, fj1 = floorf(ty1);
                int j0 = (int)fj0, j1 = (int)fj1;
                float f0 = ty0 - fj0, f1 = ty1 - fj1;
                float tx0 = l_x0[i] * INVB, g0 = floorf(tx0);
                float tx1 = l_x1[i] * INVB, g1 = floorf(tx1);
                int i0 = (int)g0, i1 = (int)g1;
                float h0 = tx0 - g0, h1 = tx1 - g1;
                float dh = l_dh[i], dv = l_dv[i];
                int   xx[4] = { i0, i0 + 1, i1, i1 + 1 };
                float ax[4] = { BSX * (1.f - h0), BSX * h0,
                               -BSX * (1.f - h1), -BSX * h1 };
                int   rr[4] = { j0, j0 + 1, j1, j1 + 1 };
                float rw[4] = { BSX * (1.f - f0), BSX * f0,
                               -BSX * (1.f - f1), -BSX * f1 };
                #pragma unroll
                for (int q = 0; q < 4; ++q) {
                    int ro = rr[q] - r0;
                    if ((unsigned)ro >= NW) continue;
                    float wh = rw[q] * dh * FXS;
                    float wv = rw[q] * dv * FXS;
                    int* bh = acci + ro * NB;
                    int* bv = acci + NW * NB + ro * NB;
                    #pragma unroll
                    for (int p = 0; p < 4; ++p) {
                        int x = xx[p];
                        if (x >= NB) continue;
                        atomicAdd(bh + x, __float2int_rn(ax[p] * wh));
                        atomicAdd(bv + x, __float2int_rn(ax[p] * wv));
                    }
                }
            }
            __syncthreads();
            if (tid == 0) lcount = 0;
            __syncthreads();
        }
    }

    // x-cumsum (convert fixed->float in-place): one wave per row (8 rows).
    const int wave = tid >> 6;
    for (int row = wave; row < 2 * NW; row += (K2_THREADS / 64)) {
        float carry = 0.f;
        #pragma unroll
        for (int seg = 0; seg < NB / 64; ++seg) {
            int idx = row * NB + seg * 64 + lane;
            float v = (float)acci[idx] * INV_FXS;
            #pragma unroll
            for (int off = 1; off < 64; off <<= 1) {
                float u = __shfl_up(v, off);
                if (lane >= off) v += u;
            }
            v += carry;
            acc[idx] = v;
            carry = __shfl(v, 63);
        }
    }
    __syncthreads();

    // Transposed store: PT[chunk][plane][x][r0..r0+4) = one float4 per (p,x).
    {
        int i = tid;                 // 512 items exactly
        int p = i >> 8;
        int x = i & 255;
        int base = p * NW * NB;
        float4 v;
        v.x = acc[base + 0 * NB + x];
        v.y = acc[base + 1 * NB + x];
        v.z = acc[base + 2 * NB + x];
        v.w = acc[base + 3 * NB + x];
        float* dst = PT + ((((long long)chunk * 2 + p) * NB + x) * NB) + r0;
        *(float4*)dst = v;
    }
}

// ---------------- K3: chunk-sum + y-cumsum + util (all coalesced) --------
__global__ __launch_bounds__(512) void yscan_util(
        const float* __restrict__ PT, float* __restrict__ utilT) {
    __shared__ float buf[2 * NB];
    const int x = blockIdx.x;
    const int plane = threadIdx.x >> 8;
    const int y = threadIdx.x & (NB - 1);
    float s = 0.f;
    #pragma unroll 8
    for (int c = 0; c < NCHUNK; ++c)
        s += PT[(((long long)c * 2 + plane) * NB + x) * NB + y];
    float* b = buf + plane * NB;
    b[y] = s;
    #pragma unroll
    for (int off = 1; off < NB; off <<= 1) {
        __syncthreads();
        float a = (y >= off) ? b[y - off] : 0.0f;
        __syncthreads();
        b[y] += a;
    }
    __syncthreads();
    if (plane == 0) {
        const float INV_CH = 1.0f / (3.90625f * 3.90625f * 1.5625f);
        const float INV_CV = 1.0f / (3.90625f * 3.90625f * 1.45f);
        float u = fmaxf(buf[y] * INV_CH, buf[NB + y] * INV_CV);
        u = fminf(fmaxf(u, 0.5f), 2.0f);
        utilT[x * NB + y] = u;
    }
}

// ---------------- K4: per-instance area (util transposed [x][y]) --------
__global__ void instance_area(const float* __restrict__ pos,
                              const float* __restrict__ nsx,
                              const float* __restrict__ nsy,
                              const float* __restrict__ utilT,
                              float* __restrict__ out,
                              int num_movable, int num_nodes) {
    int i = blockIdx.x * blockDim.x + threadIdx.x;
    if (i >= num_movable) return;
    const float BSX = 3.90625f;
    const float INVB = 1.0f / 3.90625f;
    float x0f = pos[i];
    float y0f = pos[num_nodes + i];
    float x1f = x0f + nsx[i];
    float y1f = y0f + nsy[i];
    int kx0 = max(0, min(NB - 1, (int)floorf(x0f * INVB)));
    int kx1 = max(0, min(NB - 1, (int)floorf(x1f * INVB)));
    int ky0 = max(0, min(NB - 1, (int)floorf(y0f * INVB)));
    int ky1 = max(0, min(NB - 1, (int)floorf(y1f * INVB)));
    float acc = 0.0f;
    for (int kx = kx0; kx <= kx1; ++kx) {
        float bx = kx * BSX;
        float ovx = fmaxf(fminf(x1f, bx + BSX) - fmaxf(x0f, bx), 0.0f);
        const float* ucol = utilT + kx * NB;
        float accy = 0.0f;
        for (int ky = ky0; ky <= ky1; ++ky) {
            float by = ky * BSX;
            float ovy = fmaxf(fminf(y1f, by + BSX) - fmaxf(y0f, by), 0.0f);
            accy += ovy * ucol[ky];
        }
        acc += accy * ovx;
    }
    out[i] = acc;
}

// ---------------- fallback (tiny workspace): round-1 style ----------------
__global__ void fb_zero(float* g, int n) {
    int i = blockIdx.x * blockDim.x + threadIdx.x;
    int stride = gridDim.x * blockDim.x;
    for (; i < n; i += stride) g[i] = 0.0f;
}

__global__ void fb_scatter(const float* __restrict__ pin_pos,
                           const float* __restrict__ net_weights,
                           const void* __restrict__ netpin_start,
                           const void* __restrict__ flat_netpin,
                           float* __restrict__ G2,
                           int num_nets, int num_pins) {
    int n = blockIdx.x * blockDim.x + threadIdx.x;
    if (n >= num_nets) return;
    const int is64 = (((const int*)netpin_start)[1] == 0);
    long long s = load_idx(netpin_start, n, is64);
    long long e = load_idx(netpin_start, n + 1, is64);
    if (e <= s) return;
    float xmn = 3e38f, xmx = -3e38f, ymn = 3e38f, ymx = -3e38f;
    for (long long p = s; p < e; ++p) {
        long long pin = load_idx(flat_netpin, p, is64);
        float px = pin_pos[pin], py = pin_pos[pin + num_pins];
        xmn = fminf(xmn, px); xmx = fmaxf(xmx, px);
        ymn = fminf(ymn, py); ymx = fmaxf(ymx, py);
    }
    float wx = xmx - xmn, wy = ymx - ymn;
    float area = fmaxf(wx * wy, 1e-6f);
    float w = net_weights[n];
    float dh = w * wx / area, dv = w * wy / area;
    const float BSX = 3.90625f, INVB = 1.0f / 3.90625f;
    int jx[4]; float ax[4]; int jy[4]; float ay[4];
    float t, fj, f; int j;
    t = xmn * INVB; fj = floorf(t); j = (int)fj; f = t - fj;
    jx[0] = j; ax[0] = BSX * (1.f - f); jx[1] = j + 1; ax[1] = BSX * f;
    t = xmx * INVB; fj = floorf(t); j = (int)fj; f = t - fj;
    jx[2] = j; ax[2] = -BSX * (1.f - f); jx[3] = j + 1; ax[3] = -BSX * f;
    t = ymn * INVB; fj = floorf(t); j = (int)fj; f = t - fj;
    jy[0] = j; ay[0] = BSX * (1.f - f); jy[1] = j + 1; ay[1] = BSX * f;
    t = ymx * INVB; fj = floorf(t); j = (int)fj; f = t - fj;
    jy[2] = j; ay[2] = -BSX * (1.f - f); jy[3] = j + 1; ay[3] = -BSX * f;
    #pragma unroll
    for (int b = 0; b < 4; ++b) {
        int y = jy[b];
        if (y < 0 || y >= NB) continue;
        #pragma unroll
        for (int a2 = 0; a2 < 4; ++a2) {
            int x = jx[a2];
            if (x < 0 || x >= NB) continue;
            float g = ax[a2] * ay[b];
            atomicAdd(&G2[(y * NB + x) * 2],     dh * g);
            atomicAdd(&G2[(y * NB + x) * 2 + 1], dv * g);
        }
    }
}

__global__ void fb_rowscan(float2* G2) {
    int y = blockIdx.x, t = threadIdx.x;
    __shared__ float sh[NB]; __shared__ float sv[NB];
    float2 v = G2[y * NB + t];
    sh[t] = v.x; sv[t] = v.y;
    #pragma unroll
    for (int off = 1; off < NB; off <<= 1) {
        __syncthreads();
        float a = (t >= off) ? sh[t - off] : 0.0f;
        float b = (t >= off) ? sv[t - off] : 0.0f;
        __syncthreads();
        sh[t] += a; sv[t] += b;
    }
    __syncthreads();
    G2[y * NB + t] = make_float2(sh[t], sv[t]);
}

__global__ void fb_colscan(const float2* __restrict__ G2, float* __restrict__ utilT) {
    int x = blockIdx.x, t = threadIdx.x;
    const float INV_CH = 1.0f / (3.90625f * 3.90625f * 1.5625f);
    const float INV_CV = 1.0f / (3.90625f * 3.90625f * 1.45f);
    __shared__ float sh[NB]; __shared__ float sv[NB];
    float2 g = G2[t * NB + x];
    sh[t] = g.x; sv[t] = g.y;
    #pragma unroll
    for (int off = 1; off < NB; off <<= 1) {
        __syncthreads();
        float a = (t >= off) ? sh[t - off] : 0.0f;
        float b = (t >= off) ? sv[t - off] : 0.0f;
        __syncthreads();
        sh[t] += a; sv[t] += b;
    }
    __syncthreads();
    float u = fmaxf(sh[t] * INV_CH, sv[t] * INV_CV);
    utilT[x * NB + t] = fminf(fmaxf(u, 0.5f), 2.0f);
}

extern "C" void kernel_launch(void* const* d_in, const int* in_sizes, int n_in,
                              void* d_out, int out_size, void* d_ws, size_t ws_size,
                              hipStream_t stream) {
    const float* pos          = (const float*)d_in[0];
    const float* pin_pos      = (const float*)d_in[1];
    const float* nsx          = (const float*)d_in[2];
    const float* nsy          = (const float*)d_in[3];
    const float* net_weights  = (const float*)d_in[4];
    const void*  netpin_start = d_in[5];
    const void*  flat_netpin  = d_in[6];
    float* out = (float*)d_out;

    int num_pins    = in_sizes[1] / 2;
    int num_nodes   = in_sizes[2];
    int num_nets    = in_sizes[4];
    int num_movable = out_size;

    // ws (floats): wmask_u64[n] (2n floats) | yb[2n] | rd[4n] |
    //              PT[16*2*NB*NB] | utilT[NB*NB]
    auto align4 = [](size_t v) { return (v + 3) & ~(size_t)3; };
    size_t mk_off = 0;
    size_t yb_off = align4(mk_off + 2LL * num_nets);
    size_t rd_off = align4(yb_off + 2LL * num_nets);
    size_t PT_off = align4(rd_off + 4LL * num_nets);
    size_t PT_f   = (size_t)NCHUNK * 2 * NB * NB;
    size_t ut_off = PT_off + PT_f;
    size_t need   = (ut_off + (size_t)NB * NB) * sizeof(float);

    if (ws_size >= need) {
        float* base = (float*)d_ws;
        unsigned long long* wmask = (unsigned long long*)(base + mk_off);
        float2*   yb    = (float2*)(base + yb_off);
        float4*   rd    = (float4*)(base + rd_off);
        float*    PT    = base + PT_off;
        float*    ut    = base + ut_off;

        int g1 = (4 * num_nets + 255) / 256;
        bbox_kernel<<<g1, 256, 0, stream>>>(pin_pos, net_weights, netpin_start,
                                            flat_netpin, wmask, yb, rd,
                                            num_nets, num_pins);
        accum8<<<NWIN * NCHUNK, K2_THREADS, 0, stream>>>(wmask, yb, rd, PT, num_nets);
        yscan_util<<<NB, 512, 0, stream>>>(PT, ut);
        int gi = (num_movable + 255) / 256;
        instance_area<<<gi, 256, 0, stream>>>(pos, nsx, nsy, ut, out,
                                              num_movable, num_nodes);
        return;
    }

    // -------- fallback: round-1 style (768KB workspace) --------
    {
        float* G2   = (float*)d_ws;
        float* util = G2 + NB * NB * 2;    // utilT [x][y]
        fb_zero<<<256, 256, 0, stream>>>(G2, NB * NB * 2);
        int gn = (num_nets + 255) / 256;
        fb_scatter<<<gn, 256, 0, stream>>>(pin_pos, net_weights, netpin_start,
                                           flat_netpin, G2, num_nets, num_pins);
        fb_rowscan<<<NB, 256, 0, stream>>>((float2*)G2);
        fb_colscan<<<NB, 256, 0, stream>>>((const float2*)G2, util);
        int gi = (num_movable + 255) / 256;
        instance_area<<<gi, 256, 0, stream>>>(pos, nsx, nsy, util, out,
                                              num_movable, num_nodes);
    }
}

// Round 17
// 35.716 us; speedup vs baseline: 1.1011x; 1.1011x over previous
//
#include <hip/hip_runtime.h>

// InstanceRouteOptimizationArea — RUDY map via impulse/cumsum trick.
// Round 17: de-serialize accum's strip loop.
// R16 neutral => window geometry flat; instruction arithmetic says splat is
// ~3-5us but accum ~17-20 => strip loop serializes cold loads behind
// barriers (13 x (wmask load + 2 barriers)), and on-hit yb/rd loads issue
// at low MLP. Fix: (1) prefetch all strips' wmask into registers up front;
// (2) compact net INDICES only; load yb/rd in the dense flush (512-thread
// parallel gathers); (3) LCAP=2048 -> typically a single flush.
// Geometry = R16 (NW=4/NWIN=64/NCHUNK=16, PT 8MB), math/FXS unchanged.

#define NB 256
#define NW 4           // rows per window
#define NWIN 64        // NB/NW
#define NCHUNK 16      // grid K2 = NWIN*NCHUNK = 1024
#define K2_THREADS 512
#define FXS 65536.0f
#define INV_FXS (1.0f / 65536.0f)
#define LCAP 2048      // LDS index-list capacity
#define LFLUSH 1536    // flush threshold
#define MAXSTRIPS 16

__device__ __forceinline__ long long load_idx(const void* p, long long i, int is64) {
    if (is64) return ((const long long*)p)[i];
    return (long long)((const int*)p)[i];
}

// ---------------- K1: per-net bbox + wmask(u64)/yb/rd ----------------
__global__ void bbox_kernel(const float* __restrict__ pin_pos,
                            const float* __restrict__ net_weights,
                            const void* __restrict__ netpin_start,
                            const void* __restrict__ flat_netpin,
                            unsigned long long* __restrict__ wmask,
                            float2* __restrict__ yb,
                            float4* __restrict__ rd,
                            int num_nets, int num_pins) {
    int gid = blockIdx.x * blockDim.x + threadIdx.x;
    int n = gid >> 2, k = gid & 3;
    if (n >= num_nets) return;
    const int is64 = (((const int*)netpin_start)[1] == 0);
    long long s = load_idx(netpin_start, n, is64);
    long long e = load_idx(netpin_start, n + 1, is64);
    float xmn = 3e38f, xmx = -3e38f, ymn = 3e38f, ymx = -3e38f;
    if (e - s == 4) {
        long long pin = load_idx(flat_netpin, s + k, is64);
        float px = pin_pos[pin], py = pin_pos[pin + num_pins];
        xmn = px; xmx = px; ymn = py; ymx = py;
    } else if (k == 0) {
        for (long long p = s; p < e; ++p) {
            long long pin = load_idx(flat_netpin, p, is64);
            float px = pin_pos[pin], py = pin_pos[pin + num_pins];
            xmn = fminf(xmn, px); xmx = fmaxf(xmx, px);
            ymn = fminf(ymn, py); ymx = fmaxf(ymx, py);
        }
    }
    #pragma unroll
    for (int m = 1; m <= 2; m <<= 1) {
        xmn = fminf(xmn, __shfl_xor(xmn, m));
        xmx = fmaxf(xmx, __shfl_xor(xmx, m));
        ymn = fminf(ymn, __shfl_xor(ymn, m));
        ymx = fmaxf(ymx, __shfl_xor(ymx, m));
    }
    if (k) return;
    if (e <= s) { wmask[n] = 0ull; return; }
    float wx = xmx - xmn, wy = ymx - ymn;
    float area = fmaxf(wx * wy, 1e-6f);
    float w = net_weights[n];
    const float INVB = 1.0f / 3.90625f;
    int j0 = (int)floorf(ymn * INVB);
    int j1 = (int)floorf(ymx * INVB);
    unsigned long long m = 0ull;
    if ((unsigned)j0 < 256u)       m |= 1ull << (j0 >> 2);
    if ((unsigned)(j0 + 1) < 256u) m |= 1ull << ((j0 + 1) >> 2);
    if ((unsigned)j1 < 256u)       m |= 1ull << (j1 >> 2);
    if ((unsigned)(j1 + 1) < 256u) m |= 1ull << ((j1 + 1) >> 2);
    wmask[n] = m;
    yb[n] = make_float2(ymn, ymx);
    rd[n] = make_float4(xmn, xmx, w * wx / area, w * wy / area);
}

// -- K2: prefetched filter + index-compaction + dense splat + x-cumsum ----
__global__ __launch_bounds__(K2_THREADS) void accum9(
        const unsigned long long* __restrict__ wmask,
        const float2* __restrict__ yb,
        const float4* __restrict__ rd,
        float* __restrict__ PT,          // [NCHUNK][2][NB(x)][NB(y)]
        int num_nets) {
    __shared__ float acc[2 * NW * NB];   // 8 KiB
    __shared__ int   l_idx[LCAP];        // 8 KiB
    __shared__ int   lcount;
    int* acci = (int*)acc;
    const int win   = blockIdx.x >> 4;   // 0..63
    const int chunk = blockIdx.x & 15;   // 0..15 (stride-16 blocks share XCD)
    const int r0    = win * NW;
    const int tid   = threadIdx.x;
    const int lane  = tid & 63;
    const float BSX  = 3.90625f;
    const float INVB = 1.0f / 3.90625f;

    for (int i = tid; i < 2 * NW * NB; i += K2_THREADS) acci[i] = 0;
    if (tid == 0) lcount = 0;

    const int c0 = (int)((long long)num_nets * chunk / NCHUNK);
    const int c1 = (int)((long long)num_nets * (chunk + 1) / NCHUNK);
    const int nstrips = (c1 - c0 + K2_THREADS - 1) / K2_THREADS;

    // Prefetch all strips' wmask (independent loads -> latency paid once).
    unsigned long long wm[MAXSTRIPS];
    #pragma unroll
    for (int s = 0; s < MAXSTRIPS; ++s) {
        int n = c0 + s * K2_THREADS + tid;
        wm[s] = (s < nstrips && n < c1) ? wmask[n] : 0ull;
    }
    __syncthreads();

    auto flush = [&](int cnt) {
        for (int i = tid; i < cnt; i += K2_THREADS) {
            int n = l_idx[i];
            float2 y = yb[n];            // dense parallel gathers (high MLP)
            float4 r = rd[n];
            float ty0 = y.x * INVB, fj0 = floorf(ty0);
            float ty1 = y.y * INVB, fj1 = floorf(ty1);
            int j0 = (int)fj0, j1 = (int)fj1;
            float f0 = ty0 - fj0, f1 = ty1 - fj1;
            float tx0 = r.x * INVB, g0 = floorf(tx0);
            float tx1 = r.y * INVB, g1 = floorf(tx1);
            int i0 = (int)g0, i1 = (int)g1;
            float h0 = tx0 - g0, h1 = tx1 - g1;
            int   xx[4] = { i0, i0 + 1, i1, i1 + 1 };
            float ax[4] = { BSX * (1.f - h0), BSX * h0,
                           -BSX * (1.f - h1), -BSX * h1 };
            int   rr[4] = { j0, j0 + 1, j1, j1 + 1 };
            float rw[4] = { BSX * (1.f - f0), BSX * f0,
                           -BSX * (1.f - f1), -BSX * f1 };
            #pragma unroll
            for (int q = 0; q < 4; ++q) {
                int ro = rr[q] - r0;
                if ((unsigned)ro >= NW) continue;
                float wh = rw[q] * r.z * FXS;
                float wv = rw[q] * r.w * FXS;
                int* bh = acci + ro * NB;
                int* bv = acci + NW * NB + ro * NB;
                #pragma unroll
                for (int p = 0; p < 4; ++p) {
                    int x = xx[p];
                    if (x >= NB) continue;
                    atomicAdd(bh + x, __float2int_rn(ax[p] * wh));
                    atomicAdd(bv + x, __float2int_rn(ax[p] * wv));
                }
            }
        }
    };

    for (int s = 0; s < nstrips; ++s) {
        int n = c0 + s * K2_THREADS + tid;
        bool hit = ((wm[s] >> win) & 1ull) != 0ull;
        unsigned long long m = __ballot(hit);
        if (m) {
            int base = 0;
            if (lane == 0) base = atomicAdd(&lcount, (int)__popcll(m));
            base = __shfl(base, 0);
            if (hit) {
                int pos = base + (int)__popcll(m & ((1ull << lane) - 1ull));
                if (pos < LCAP) l_idx[pos] = n;
            }
        }
        if (s == nstrips - 1 || lcount >= LFLUSH) {   // lcount read is racy-safe:
            __syncthreads();                           // re-read after barrier
            int cnt = lcount; if (cnt > LCAP) cnt = LCAP;
            flush(cnt);
            __syncthreads();
            if (tid == 0) lcount = 0;
            __syncthreads();
        }
    }

    // x-cumsum (convert fixed->float in-place): one wave per row (8 rows).
    const int wave = tid >> 6;
    for (int row = wave; row < 2 * NW; row += (K2_THREADS / 64)) {
        float carry = 0.f;
        #pragma unroll
        for (int seg = 0; seg < NB / 64; ++seg) {
            int idx = row * NB + seg * 64 + lane;
            float v = (float)acci[idx] * INV_FXS;
            #pragma unroll
            for (int off = 1; off < 64; off <<= 1) {
                float u = __shfl_up(v, off);
                if (lane >= off) v += u;
            }
            v += carry;
            acc[idx] = v;
            carry = __shfl(v, 63);
        }
    }
    __syncthreads();

    // Transposed store: PT[chunk][plane][x][r0..r0+4) = one float4 per (p,x).
    {
        int i = tid;                 // 512 items exactly
        int p = i >> 8;
        int x = i & 255;
        int base = p * NW * NB;
        float4 v;
        v.x = acc[base + 0 * NB + x];
        v.y = acc[base + 1 * NB + x];
        v.z = acc[base + 2 * NB + x];
        v.w = acc[base + 3 * NB + x];
        float* dst = PT + ((((long long)chunk * 2 + p) * NB + x) * NB) + r0;
        *(float4*)dst = v;
    }
}

// ---------------- K3: chunk-sum + y-cumsum + util (all coalesced) --------
__global__ __launch_bounds__(512) void yscan_util(
        const float* __restrict__ PT, float* __restrict__ utilT) {
    __shared__ float buf[2 * NB];
    const int x = blockIdx.x;
    const int plane = threadIdx.x >> 8;
    const int y = threadIdx.x & (NB - 1);
    float s = 0.f;
    #pragma unroll 8
    for (int c = 0; c < NCHUNK; ++c)
        s += PT[(((long long)c * 2 + plane) * NB + x) * NB + y];
    float* b = buf + plane * NB;
    b[y] = s;
    #pragma unroll
    for (int off = 1; off < NB; off <<= 1) {
        __syncthreads();
        float a = (y >= off) ? b[y - off] : 0.0f;
        __syncthreads();
        b[y] += a;
    }
    __syncthreads();
    if (plane == 0) {
        const float INV_CH = 1.0f / (3.90625f * 3.90625f * 1.5625f);
        const float INV_CV = 1.0f / (3.90625f * 3.90625f * 1.45f);
        float u = fmaxf(buf[y] * INV_CH, buf[NB + y] * INV_CV);
        u = fminf(fmaxf(u, 0.5f), 2.0f);
        utilT[x * NB + y] = u;
    }
}

// ---------------- K4: per-instance area (util transposed [x][y]) --------
__global__ void instance_area(const float* __restrict__ pos,
                              const float* __restrict__ nsx,
                              const float* __restrict__ nsy,
                              const float* __restrict__ utilT,
                              float* __restrict__ out,
                              int num_movable, int num_nodes) {
    int i = blockIdx.x * blockDim.x + threadIdx.x;
    if (i >= num_movable) return;
    const float BSX = 3.90625f;
    const float INVB = 1.0f / 3.90625f;
    float x0f = pos[i];
    float y0f = pos[num_nodes + i];
    float x1f = x0f + nsx[i];
    float y1f = y0f + nsy[i];
    int kx0 = max(0, min(NB - 1, (int)floorf(x0f * INVB)));
    int kx1 = max(0, min(NB - 1, (int)floorf(x1f * INVB)));
    int ky0 = max(0, min(NB - 1, (int)floorf(y0f * INVB)));
    int ky1 = max(0, min(NB - 1, (int)floorf(y1f * INVB)));
    float acc = 0.0f;
    for (int kx = kx0; kx <= kx1; ++kx) {
        float bx = kx * BSX;
        float ovx = fmaxf(fminf(x1f, bx + BSX) - fmaxf(x0f, bx), 0.0f);
        const float* ucol = utilT + kx * NB;
        float accy = 0.0f;
        for (int ky = ky0; ky <= ky1; ++ky) {
            float by = ky * BSX;
            float ovy = fmaxf(fminf(y1f, by + BSX) - fmaxf(y0f, by), 0.0f);
            accy += ovy * ucol[ky];
        }
        acc += accy * ovx;
    }
    out[i] = acc;
}

// ---------------- fallback (tiny workspace): round-1 style ----------------
__global__ void fb_zero(float* g, int n) {
    int i = blockIdx.x * blockDim.x + threadIdx.x;
    int stride = gridDim.x * blockDim.x;
    for (; i < n; i += stride) g[i] = 0.0f;
}

__global__ void fb_scatter(const float* __restrict__ pin_pos,
                           const float* __restrict__ net_weights,
                           const void* __restrict__ netpin_start,
                           const void* __restrict__ flat_netpin,
                           float* __restrict__ G2,
                           int num_nets, int num_pins) {
    int n = blockIdx.x * blockDim.x + threadIdx.x;
    if (n >= num_nets) return;
    const int is64 = (((const int*)netpin_start)[1] == 0);
    long long s = load_idx(netpin_start, n, is64);
    long long e = load_idx(netpin_start, n + 1, is64);
    if (e <= s) return;
    float xmn = 3e38f, xmx = -3e38f, ymn = 3e38f, ymx = -3e38f;
    for (long long p = s; p < e; ++p) {
        long long pin = load_idx(flat_netpin, p, is64);
        float px = pin_pos[pin], py = pin_pos[pin + num_pins];
        xmn = fminf(xmn, px); xmx = fmaxf(xmx, px);
        ymn = fminf(ymn, py); ymx = fmaxf(ymx, py);
    }
    float wx = xmx - xmn, wy = ymx - ymn;
    float area = fmaxf(wx * wy, 1e-6f);
    float w = net_weights[n];
    float dh = w * wx / area, dv = w * wy / area;
    const float BSX = 3.90625f, INVB = 1.0f / 3.90625f;
    int jx[4]; float ax[4]; int jy[4]; float ay[4];
    float t, fj, f; int j;
    t = xmn * INVB; fj = floorf(t); j = (int)fj; f = t - fj;
    jx[0] = j; ax[0] = BSX * (1.f - f); jx[1] = j + 1; ax[1] = BSX * f;
    t = xmx * INVB; fj = floorf(t); j = (int)fj; f = t - fj;
    jx[2] = j; ax[2] = -BSX * (1.f - f); jx[3] = j + 1; ax[3] = -BSX * f;
    t = ymn * INVB; fj = floorf(t); j = (int)fj; f = t - fj;
    jy[0] = j; ay[0] = BSX * (1.f - f); jy[1] = j + 1; ay[1] = BSX * f;
    t = ymx * INVB; fj = floorf(t); j = (int)fj; f = t - fj;
    jy[2] = j; ay[2] = -BSX * (1.f - f); jy[3] = j + 1; ay[3] = -BSX * f;
    #pragma unroll
    for (int b = 0; b < 4; ++b) {
        int y = jy[b];
        if (y < 0 || y >= NB) continue;
        #pragma unroll
        for (int a2 = 0; a2 < 4; ++a2) {
            int x = jx[a2];
            if (x < 0 || x >= NB) continue;
            float g = ax[a2] * ay[b];
            atomicAdd(&G2[(y * NB + x) * 2],     dh * g);
            atomicAdd(&G2[(y * NB + x) * 2 + 1], dv * g);
        }
    }
}

__global__ void fb_rowscan(float2* G2) {
    int y = blockIdx.x, t = threadIdx.x;
    __shared__ float sh[NB]; __shared__ float sv[NB];
    float2 v = G2[y * NB + t];
    sh[t] = v.x; sv[t] = v.y;
    #pragma unroll
    for (int off = 1; off < NB; off <<= 1) {
        __syncthreads();
        float a = (t >= off) ? sh[t - off] : 0.0f;
        float b = (t >= off) ? sv[t - off] : 0.0f;
        __syncthreads();
        sh[t] += a; sv[t] += b;
    }
    __syncthreads();
    G2[y * NB + t] = make_float2(sh[t], sv[t]);
}

__global__ void fb_colscan(const float2* __restrict__ G2, float* __restrict__ utilT) {
    int x = blockIdx.x, t = threadIdx.x;
    const float INV_CH = 1.0f / (3.90625f * 3.90625f * 1.5625f);
    const float INV_CV = 1.0f / (3.90625f * 3.90625f * 1.45f);
    __shared__ float sh[NB]; __shared__ float sv[NB];
    float2 g = G2[t * NB + x];
    sh[t] = g.x; sv[t] = g.y;
    #pragma unroll
    for (int off = 1; off < NB; off <<= 1) {
        __syncthreads();
        float a = (t >= off) ? sh[t - off] : 0.0f;
        float b = (t >= off) ? sv[t - off] : 0.0f;
        __syncthreads();
        sh[t] += a; sv[t] += b;
    }
    __syncthreads();
    float u = fmaxf(sh[t] * INV_CH, sv[t] * INV_CV);
    utilT[x * NB + t] = fminf(fmaxf(u, 0.5f), 2.0f);
}

extern "C" void kernel_launch(void* const* d_in, const int* in_sizes, int n_in,
                              void* d_out, int out_size, void* d_ws, size_t ws_size,
                              hipStream_t stream) {
    const float* pos          = (const float*)d_in[0];
    const float* pin_pos      = (const float*)d_in[1];
    const float* nsx          = (const float*)d_in[2];
    const float* nsy          = (const float*)d_in[3];
    const float* net_weights  = (const float*)d_in[4];
    const void*  netpin_start = d_in[5];
    const void*  flat_netpin  = d_in[6];
    float* out = (float*)d_out;

    int num_pins    = in_sizes[1] / 2;
    int num_nodes   = in_sizes[2];
    int num_nets    = in_sizes[4];
    int num_movable = out_size;

    // ws (floats): wmask_u64[n] (2n floats) | yb[2n] | rd[4n] |
    //              PT[16*2*NB*NB] | utilT[NB*NB]
    auto align4 = [](size_t v) { return (v + 3) & ~(size_t)3; };
    size_t mk_off = 0;
    size_t yb_off = align4(mk_off + 2LL * num_nets);
    size_t rd_off = align4(yb_off + 2LL * num_nets);
    size_t PT_off = align4(rd_off + 4LL * num_nets);
    size_t PT_f   = (size_t)NCHUNK * 2 * NB * NB;
    size_t ut_off = PT_off + PT_f;
    size_t need   = (ut_off + (size_t)NB * NB) * sizeof(float);

    // Guard: prefetch array must cover all strips.
    bool strips_ok = ((num_nets + NCHUNK - 1) / NCHUNK + K2_THREADS - 1) / K2_THREADS
                     <= MAXSTRIPS;

    if (ws_size >= need && strips_ok) {
        float* base = (float*)d_ws;
        unsigned long long* wmask = (unsigned long long*)(base + mk_off);
        float2*   yb    = (float2*)(base + yb_off);
        float4*   rd    = (float4*)(base + rd_off);
        float*    PT    = base + PT_off;
        float*    ut    = base + ut_off;

        int g1 = (4 * num_nets + 255) / 256;
        bbox_kernel<<<g1, 256, 0, stream>>>(pin_pos, net_weights, netpin_start,
                                            flat_netpin, wmask, yb, rd,
                                            num_nets, num_pins);
        accum9<<<NWIN * NCHUNK, K2_THREADS, 0, stream>>>(wmask, yb, rd, PT, num_nets);
        yscan_util<<<NB, 512, 0, stream>>>(PT, ut);
        int gi = (num_movable + 255) / 256;
        instance_area<<<gi, 256, 0, stream>>>(pos, nsx, nsy, ut, out,
                                              num_movable, num_nodes);
        return;
    }

    // -------- fallback: round-1 style (768KB workspace) --------
    {
        float* G2   = (float*)d_ws;
        float* util = G2 + NB * NB * 2;    // utilT [x][y]
        fb_zero<<<256, 256, 0, stream>>>(G2, NB * NB * 2);
        int gn = (num_nets + 255) / 256;
        fb_scatter<<<gn, 256, 0, stream>>>(pin_pos, net_weights, netpin_start,
                                           flat_netpin, G2, num_nets, num_pins);
        fb_rowscan<<<NB, 256, 0, stream>>>((float2*)G2);
        fb_colscan<<<NB, 256, 0, stream>>>((const float2*)G2, util);
        int gi = (num_movable + 255) / 256;
        instance_area<<<gi, 256, 0, stream>>>(pos, nsx, nsy, util, out,
                                              num_movable, num_nodes);
    }
}

// Round 18
// 35.051 us; speedup vs baseline: 1.1220x; 1.0190x over previous
//
#include <hip/hip_runtime.h>

// InstanceRouteOptimizationArea — RUDY map via impulse/cumsum trick.
// Round 18: NCHUNK 16->8 @ 1024 threads (one residency generation, chunk==XCD,
// PT halves to 4MB), plane-split dense flush (13 LDS atomics/thread, not 26),
// and a barrier-correct flush decision (R17's lcount check could hit
// __syncthreads divergently - latent hang, fixed).
// Math/FXS/filter structure unchanged from R17 (proven 35.7us).

#define NB 256
#define NW 4           // rows per window
#define NWIN 64        // NB/NW
#define NCHUNK 8       // == XCD count; grid K2 = NWIN*NCHUNK = 512
#define K2_THREADS 1024
#define FXS 65536.0f
#define INV_FXS (1.0f / 65536.0f)
#define LCAP 2048      // LDS index-list capacity
#define LFLUSH 1024    // flush threshold (LCAP - K2_THREADS appends headroom)
#define MAXSTRIPS 16

__device__ __forceinline__ long long load_idx(const void* p, long long i, int is64) {
    if (is64) return ((const long long*)p)[i];
    return (long long)((const int*)p)[i];
}

// ---------------- K1: per-net bbox + wmask(u64)/yb/rd ----------------
__global__ void bbox_kernel(const float* __restrict__ pin_pos,
                            const float* __restrict__ net_weights,
                            const void* __restrict__ netpin_start,
                            const void* __restrict__ flat_netpin,
                            unsigned long long* __restrict__ wmask,
                            float2* __restrict__ yb,
                            float4* __restrict__ rd,
                            int num_nets, int num_pins) {
    int gid = blockIdx.x * blockDim.x + threadIdx.x;
    int n = gid >> 2, k = gid & 3;
    if (n >= num_nets) return;
    const int is64 = (((const int*)netpin_start)[1] == 0);
    long long s = load_idx(netpin_start, n, is64);
    long long e = load_idx(netpin_start, n + 1, is64);
    float xmn = 3e38f, xmx = -3e38f, ymn = 3e38f, ymx = -3e38f;
    if (e - s == 4) {
        long long pin = load_idx(flat_netpin, s + k, is64);
        float px = pin_pos[pin], py = pin_pos[pin + num_pins];
        xmn = px; xmx = px; ymn = py; ymx = py;
    } else if (k == 0) {
        for (long long p = s; p < e; ++p) {
            long long pin = load_idx(flat_netpin, p, is64);
            float px = pin_pos[pin], py = pin_pos[pin + num_pins];
            xmn = fminf(xmn, px); xmx = fmaxf(xmx, px);
            ymn = fminf(ymn, py); ymx = fmaxf(ymx, py);
        }
    }
    #pragma unroll
    for (int m = 1; m <= 2; m <<= 1) {
        xmn = fminf(xmn, __shfl_xor(xmn, m));
        xmx = fmaxf(xmx, __shfl_xor(xmx, m));
        ymn = fminf(ymn, __shfl_xor(ymn, m));
        ymx = fmaxf(ymx, __shfl_xor(ymx, m));
    }
    if (k) return;
    if (e <= s) { wmask[n] = 0ull; return; }
    float wx = xmx - xmn, wy = ymx - ymn;
    float area = fmaxf(wx * wy, 1e-6f);
    float w = net_weights[n];
    const float INVB = 1.0f / 3.90625f;
    int j0 = (int)floorf(ymn * INVB);
    int j1 = (int)floorf(ymx * INVB);
    unsigned long long m = 0ull;
    if ((unsigned)j0 < 256u)       m |= 1ull << (j0 >> 2);
    if ((unsigned)(j0 + 1) < 256u) m |= 1ull << ((j0 + 1) >> 2);
    if ((unsigned)j1 < 256u)       m |= 1ull << (j1 >> 2);
    if ((unsigned)(j1 + 1) < 256u) m |= 1ull << ((j1 + 1) >> 2);
    wmask[n] = m;
    yb[n] = make_float2(ymn, ymx);
    rd[n] = make_float4(xmn, xmx, w * wx / area, w * wy / area);
}

// -- K2: prefetched filter + index compaction + plane-split dense splat ----
__global__ __launch_bounds__(K2_THREADS) void accum10(
        const unsigned long long* __restrict__ wmask,
        const float2* __restrict__ yb,
        const float4* __restrict__ rd,
        float* __restrict__ PT,          // [NCHUNK][2][NB(x)][NB(y)]
        int num_nets) {
    __shared__ float acc[2 * NW * NB];   // 8 KiB
    __shared__ int   l_idx[LCAP];        // 8 KiB
    __shared__ int   lcount;
    int* acci = (int*)acc;
    const int win   = blockIdx.x >> 3;   // 0..63
    const int chunk = blockIdx.x & 7;    // 0..7 == XCD id (round-robin blocks)
    const int r0    = win * NW;
    const int tid   = threadIdx.x;
    const int lane  = tid & 63;
    const float BSX  = 3.90625f;
    const float INVB = 1.0f / 3.90625f;

    for (int i = tid; i < 2 * NW * NB; i += K2_THREADS) acci[i] = 0;
    if (tid == 0) lcount = 0;

    const int c0 = (int)((long long)num_nets * chunk / NCHUNK);
    const int c1 = (int)((long long)num_nets * (chunk + 1) / NCHUNK);
    const int nstrips = (c1 - c0 + K2_THREADS - 1) / K2_THREADS;

    // Prefetch all strips' wmask (independent loads -> one latency).
    unsigned long long wm[MAXSTRIPS];
    #pragma unroll
    for (int s = 0; s < MAXSTRIPS; ++s) {
        int n = c0 + s * K2_THREADS + tid;
        wm[s] = (s < nstrips && n < c1) ? wmask[n] : 0ull;
    }
    __syncthreads();

    // Plane-split flush: 2 threads per record (pl 0 = h, pl 1 = v).
    auto flush = [&](int cnt) {
        for (int ii = tid; ii < 2 * cnt; ii += K2_THREADS) {
            int i  = (ii < cnt) ? ii : ii - cnt;
            int pl = (ii < cnt) ? 0 : 1;
            int n = l_idx[i];
            float2 y = yb[n];
            float4 r = rd[n];
            float ty0 = y.x * INVB, fj0 = floorf(ty0);
            float ty1 = y.y * INVB, fj1 = floorf(ty1);
            int j0 = (int)fj0, j1 = (int)fj1;
            float f0 = ty0 - fj0, f1 = ty1 - fj1;
            float tx0 = r.x * INVB, g0 = floorf(tx0);
            float tx1 = r.y * INVB, g1 = floorf(tx1);
            int i0 = (int)g0, i1 = (int)g1;
            float h0 = tx0 - g0, h1 = tx1 - g1;
            float d = pl ? r.w : r.z;
            int* bp = acci + pl * (NW * NB);
            int   xx[4] = { i0, i0 + 1, i1, i1 + 1 };
            float ax[4] = { BSX * (1.f - h0), BSX * h0,
                           -BSX * (1.f - h1), -BSX * h1 };
            int   rr[4] = { j0, j0 + 1, j1, j1 + 1 };
            float rw[4] = { BSX * (1.f - f0), BSX * f0,
                           -BSX * (1.f - f1), -BSX * f1 };
            #pragma unroll
            for (int q = 0; q < 4; ++q) {
                int ro = rr[q] - r0;
                if ((unsigned)ro >= NW) continue;
                float wd = rw[q] * d * FXS;
                int* b2 = bp + ro * NB;
                #pragma unroll
                for (int p = 0; p < 4; ++p) {
                    int x = xx[p];
                    if (x >= NB) continue;
                    atomicAdd(b2 + x, __float2int_rn(ax[p] * wd));
                }
            }
        }
    };

    for (int s = 0; s < nstrips; ++s) {
        int n = c0 + s * K2_THREADS + tid;
        bool hit = ((wm[s] >> win) & 1ull) != 0ull;
        unsigned long long m = __ballot(hit);
        if (m) {
            int base = 0;
            if (lane == 0) base = atomicAdd(&lcount, (int)__popcll(m));
            base = __shfl(base, 0);
            if (hit) {
                int pos = base + (int)__popcll(m & ((1ull << lane) - 1ull));
                if (pos < LCAP) l_idx[pos] = n;
            }
        }
        __syncthreads();                       // uniform view of lcount
        int cnt = lcount; if (cnt > LCAP) cnt = LCAP;
        if (cnt >= LFLUSH || s == nstrips - 1) {
            flush(cnt);
            __syncthreads();
            if (tid == 0) lcount = 0;
            __syncthreads();
        }
    }

    // x-cumsum (convert fixed->float in-place): one wave per row (8 rows).
    const int wave = tid >> 6;
    for (int row = wave; row < 2 * NW; row += (K2_THREADS / 64)) {
        float carry = 0.f;
        #pragma unroll
        for (int seg = 0; seg < NB / 64; ++seg) {
            int idx = row * NB + seg * 64 + lane;
            float v = (float)acci[idx] * INV_FXS;
            #pragma unroll
            for (int off = 1; off < 64; off <<= 1) {
                float u = __shfl_up(v, off);
                if (lane >= off) v += u;
            }
            v += carry;
            acc[idx] = v;
            carry = __shfl(v, 63);
        }
    }
    __syncthreads();

    // Transposed store: PT[chunk][plane][x][r0..r0+4) = one float4 per (p,x).
    if (tid < 512) {
        int p = tid >> 8;
        int x = tid & 255;
        int base = p * NW * NB;
        float4 v;
        v.x = acc[base + 0 * NB + x];
        v.y = acc[base + 1 * NB + x];
        v.z = acc[base + 2 * NB + x];
        v.w = acc[base + 3 * NB + x];
        float* dst = PT + ((((long long)chunk * 2 + p) * NB + x) * NB) + r0;
        *(float4*)dst = v;
    }
}

// ---------------- K3: chunk-sum + y-cumsum + util (all coalesced) --------
__global__ __launch_bounds__(512) void yscan_util(
        const float* __restrict__ PT, float* __restrict__ utilT) {
    __shared__ float buf[2 * NB];
    const int x = blockIdx.x;
    const int plane = threadIdx.x >> 8;
    const int y = threadIdx.x & (NB - 1);
    float s = 0.f;
    #pragma unroll
    for (int c = 0; c < NCHUNK; ++c)
        s += PT[(((long long)c * 2 + plane) * NB + x) * NB + y];
    float* b = buf + plane * NB;
    b[y] = s;
    #pragma unroll
    for (int off = 1; off < NB; off <<= 1) {
        __syncthreads();
        float a = (y >= off) ? b[y - off] : 0.0f;
        __syncthreads();
        b[y] += a;
    }
    __syncthreads();
    if (plane == 0) {
        const float INV_CH = 1.0f / (3.90625f * 3.90625f * 1.5625f);
        const float INV_CV = 1.0f / (3.90625f * 3.90625f * 1.45f);
        float u = fmaxf(buf[y] * INV_CH, buf[NB + y] * INV_CV);
        u = fminf(fmaxf(u, 0.5f), 2.0f);
        utilT[x * NB + y] = u;
    }
}

// ---------------- K4: per-instance area (util transposed [x][y]) --------
__global__ void instance_area(const float* __restrict__ pos,
                              const float* __restrict__ nsx,
                              const float* __restrict__ nsy,
                              const float* __restrict__ utilT,
                              float* __restrict__ out,
                              int num_movable, int num_nodes) {
    int i = blockIdx.x * blockDim.x + threadIdx.x;
    if (i >= num_movable) return;
    const float BSX = 3.90625f;
    const float INVB = 1.0f / 3.90625f;
    float x0f = pos[i];
    float y0f = pos[num_nodes + i];
    float x1f = x0f + nsx[i];
    float y1f = y0f + nsy[i];
    int kx0 = max(0, min(NB - 1, (int)floorf(x0f * INVB)));
    int kx1 = max(0, min(NB - 1, (int)floorf(x1f * INVB)));
    int ky0 = max(0, min(NB - 1, (int)floorf(y0f * INVB)));
    int ky1 = max(0, min(NB - 1, (int)floorf(y1f * INVB)));
    float acc = 0.0f;
    for (int kx = kx0; kx <= kx1; ++kx) {
        float bx = kx * BSX;
        float ovx = fmaxf(fminf(x1f, bx + BSX) - fmaxf(x0f, bx), 0.0f);
        const float* ucol = utilT + kx * NB;
        float accy = 0.0f;
        for (int ky = ky0; ky <= ky1; ++ky) {
            float by = ky * BSX;
            float ovy = fmaxf(fminf(y1f, by + BSX) - fmaxf(y0f, by), 0.0f);
            accy += ovy * ucol[ky];
        }
        acc += accy * ovx;
    }
    out[i] = acc;
}

// ---------------- fallback (tiny workspace): round-1 style ----------------
__global__ void fb_zero(float* g, int n) {
    int i = blockIdx.x * blockDim.x + threadIdx.x;
    int stride = gridDim.x * blockDim.x;
    for (; i < n; i += stride) g[i] = 0.0f;
}

__global__ void fb_scatter(const float* __restrict__ pin_pos,
                           const float* __restrict__ net_weights,
                           const void* __restrict__ netpin_start,
                           const void* __restrict__ flat_netpin,
                           float* __restrict__ G2,
                           int num_nets, int num_pins) {
    int n = blockIdx.x * blockDim.x + threadIdx.x;
    if (n >= num_nets) return;
    const int is64 = (((const int*)netpin_start)[1] == 0);
    long long s = load_idx(netpin_start, n, is64);
    long long e = load_idx(netpin_start, n + 1, is64);
    if (e <= s) return;
    float xmn = 3e38f, xmx = -3e38f, ymn = 3e38f, ymx = -3e38f;
    for (long long p = s; p < e; ++p) {
        long long pin = load_idx(flat_netpin, p, is64);
        float px = pin_pos[pin], py = pin_pos[pin + num_pins];
        xmn = fminf(xmn, px); xmx = fmaxf(xmx, px);
        ymn = fminf(ymn, py); ymx = fmaxf(ymx, py);
    }
    float wx = xmx - xmn, wy = ymx - ymn;
    float area = fmaxf(wx * wy, 1e-6f);
    float w = net_weights[n];
    float dh = w * wx / area, dv = w * wy / area;
    const float BSX = 3.90625f, INVB = 1.0f / 3.90625f;
    int jx[4]; float ax[4]; int jy[4]; float ay[4];
    float t, fj, f; int j;
    t = xmn * INVB; fj = floorf(t); j = (int)fj; f = t - fj;
    jx[0] = j; ax[0] = BSX * (1.f - f); jx[1] = j + 1; ax[1] = BSX * f;
    t = xmx * INVB; fj = floorf(t); j = (int)fj; f = t - fj;
    jx[2] = j; ax[2] = -BSX * (1.f - f); jx[3] = j + 1; ax[3] = -BSX * f;
    t = ymn * INVB; fj = floorf(t); j = (int)fj; f = t - fj;
    jy[0] = j; ay[0] = BSX * (1.f - f); jy[1] = j + 1; ay[1] = BSX * f;
    t = ymx * INVB; fj = floorf(t); j = (int)fj; f = t - fj;
    jy[2] = j; ay[2] = -BSX * (1.f - f); jy[3] = j + 1; ay[3] = -BSX * f;
    #pragma unroll
    for (int b = 0; b < 4; ++b) {
        int y = jy[b];
        if (y < 0 || y >= NB) continue;
        #pragma unroll
        for (int a2 = 0; a2 < 4; ++a2) {
            int x = jx[a2];
            if (x < 0 || x >= NB) continue;
            float g = ax[a2] * ay[b];
            atomicAdd(&G2[(y * NB + x) * 2],     dh * g);
            atomicAdd(&G2[(y * NB + x) * 2 + 1], dv * g);
        }
    }
}

__global__ void fb_rowscan(float2* G2) {
    int y = blockIdx.x, t = threadIdx.x;
    __shared__ float sh[NB]; __shared__ float sv[NB];
    float2 v = G2[y * NB + t];
    sh[t] = v.x; sv[t] = v.y;
    #pragma unroll
    for (int off = 1; off < NB; off <<= 1) {
        __syncthreads();
        float a = (t >= off) ? sh[t - off] : 0.0f;
        float b = (t >= off) ? sv[t - off] : 0.0f;
        __syncthreads();
        sh[t] += a; sv[t] += b;
    }
    __syncthreads();
    G2[y * NB + t] = make_float2(sh[t], sv[t]);
}

__global__ void fb_colscan(const float2* __restrict__ G2, float* __restrict__ utilT) {
    int x = blockIdx.x, t = threadIdx.x;
    const float INV_CH = 1.0f / (3.90625f * 3.90625f * 1.5625f);
    const float INV_CV = 1.0f / (3.90625f * 3.90625f * 1.45f);
    __shared__ float sh[NB]; __shared__ float sv[NB];
    float2 g = G2[t * NB + x];
    sh[t] = g.x; sv[t] = g.y;
    #pragma unroll
    for (int off = 1; off < NB; off <<= 1) {
        __syncthreads();
        float a = (t >= off) ? sh[t - off] : 0.0f;
        float b = (t >= off) ? sv[t - off] : 0.0f;
        __syncthreads();
        sh[t] += a; sv[t] += b;
    }
    __syncthreads();
    float u = fmaxf(sh[t] * INV_CH, sv[t] * INV_CV);
    utilT[x * NB + t] = fminf(fmaxf(u, 0.5f), 2.0f);
}

extern "C" void kernel_launch(void* const* d_in, const int* in_sizes, int n_in,
                              void* d_out, int out_size, void* d_ws, size_t ws_size,
                              hipStream_t stream) {
    const float* pos          = (const float*)d_in[0];
    const float* pin_pos      = (const float*)d_in[1];
    const float* nsx          = (const float*)d_in[2];
    const float* nsy          = (const float*)d_in[3];
    const float* net_weights  = (const float*)d_in[4];
    const void*  netpin_start = d_in[5];
    const void*  flat_netpin  = d_in[6];
    float* out = (float*)d_out;

    int num_pins    = in_sizes[1] / 2;
    int num_nodes   = in_sizes[2];
    int num_nets    = in_sizes[4];
    int num_movable = out_size;

    // ws (floats): wmask_u64[n] (2n floats) | yb[2n] | rd[4n] |
    //              PT[8*2*NB*NB] | utilT[NB*NB]
    auto align4 = [](size_t v) { return (v + 3) & ~(size_t)3; };
    size_t mk_off = 0;
    size_t yb_off = align4(mk_off + 2LL * num_nets);
    size_t rd_off = align4(yb_off + 2LL * num_nets);
    size_t PT_off = align4(rd_off + 4LL * num_nets);
    size_t PT_f   = (size_t)NCHUNK * 2 * NB * NB;
    size_t ut_off = PT_off + PT_f;
    size_t need   = (ut_off + (size_t)NB * NB) * sizeof(float);

    // Guard: prefetch array must cover all strips.
    bool strips_ok = ((num_nets + NCHUNK - 1) / NCHUNK + K2_THREADS - 1) / K2_THREADS
                     <= MAXSTRIPS;

    if (ws_size >= need && strips_ok) {
        float* base = (float*)d_ws;
        unsigned long long* wmask = (unsigned long long*)(base + mk_off);
        float2*   yb    = (float2*)(base + yb_off);
        float4*   rd    = (float4*)(base + rd_off);
        float*    PT    = base + PT_off;
        float*    ut    = base + ut_off;

        int g1 = (4 * num_nets + 255) / 256;
        bbox_kernel<<<g1, 256, 0, stream>>>(pin_pos, net_weights, netpin_start,
                                            flat_netpin, wmask, yb, rd,
                                            num_nets, num_pins);
        accum10<<<NWIN * NCHUNK, K2_THREADS, 0, stream>>>(wmask, yb, rd, PT, num_nets);
        yscan_util<<<NB, 512, 0, stream>>>(PT, ut);
        int gi = (num_movable + 255) / 256;
        instance_area<<<gi, 256, 0, stream>>>(pos, nsx, nsy, ut, out,
                                              num_movable, num_nodes);
        return;
    }

    // -------- fallback: round-1 style (768KB workspace) --------
    {
        float* G2   = (float*)d_ws;
        float* util = G2 + NB * NB * 2;    // utilT [x][y]
        fb_zero<<<256, 256, 0, stream>>>(G2, NB * NB * 2);
        int gn = (num_nets + 255) / 256;
        fb_scatter<<<gn, 256, 0, stream>>>(pin_pos, net_weights, netpin_start,
                                           flat_netpin, G2, num_nets, num_pins);
        fb_rowscan<<<NB, 256, 0, stream>>>((float2*)G2);
        fb_colscan<<<NB, 256, 0, stream>>>((const float2*)G2, util);
        int gi = (num_movable + 255) / 256;
        instance_area<<<gi, 256, 0, stream>>>(pos, nsx, nsy, util, out,
                                              num_movable, num_nodes);
    }
}

// Round 19
// 32.485 us; speedup vs baseline: 1.2106x; 1.0790x over previous
//
#include <hip/hip_runtime.h>

// InstanceRouteOptimizationArea — RUDY map via impulse/cumsum trick.
// Round 19: barrier-free append + merged records.
// R18 ledger: accum ~10-12us; its 13 per-strip barriers existed only to
// guard mid-flushes that never trigger (worst-case hits ~900 << LCAP).
// Remove them: appends are wave-atomic (LDS lcount), splat is i32
// fixed-point => order-independent, bit-deterministic. Single final flush.
// Also merge yb+rd into contiguous float4 pairs (1 cache line/record).

#define NB 256
#define NW 4           // rows per window
#define NWIN 64        // NB/NW
#define NCHUNK 8       // == XCD count; grid K2 = NWIN*NCHUNK = 512
#define K2_THREADS 1024
#define FXS 65536.0f
#define INV_FXS (1.0f / 65536.0f)
#define LCAP 3072      // LDS index-list capacity (worst-case ~900)
#define MAXSTRIPS 16

__device__ __forceinline__ long long load_idx(const void* p, long long i, int is64) {
    if (is64) return ((const long long*)p)[i];
    return (long long)((const int*)p)[i];
}

// ---------------- K1: per-net bbox + wmask(u64) + merged rec ----------------
__global__ void bbox_kernel(const float* __restrict__ pin_pos,
                            const float* __restrict__ net_weights,
                            const void* __restrict__ netpin_start,
                            const void* __restrict__ flat_netpin,
                            unsigned long long* __restrict__ wmask,
                            float4* __restrict__ rec,    // [2n]: {ymn,ymx,xmn,xmx},{dh,dv,-,-}
                            int num_nets, int num_pins) {
    int gid = blockIdx.x * blockDim.x + threadIdx.x;
    int n = gid >> 2, k = gid & 3;
    if (n >= num_nets) return;
    const int is64 = (((const int*)netpin_start)[1] == 0);
    long long s = load_idx(netpin_start, n, is64);
    long long e = load_idx(netpin_start, n + 1, is64);
    float xmn = 3e38f, xmx = -3e38f, ymn = 3e38f, ymx = -3e38f;
    if (e - s == 4) {
        long long pin = load_idx(flat_netpin, s + k, is64);
        float px = pin_pos[pin], py = pin_pos[pin + num_pins];
        xmn = px; xmx = px; ymn = py; ymx = py;
    } else if (k == 0) {
        for (long long p = s; p < e; ++p) {
            long long pin = load_idx(flat_netpin, p, is64);
            float px = pin_pos[pin], py = pin_pos[pin + num_pins];
            xmn = fminf(xmn, px); xmx = fmaxf(xmx, px);
            ymn = fminf(ymn, py); ymx = fmaxf(ymx, py);
        }
    }
    #pragma unroll
    for (int m = 1; m <= 2; m <<= 1) {
        xmn = fminf(xmn, __shfl_xor(xmn, m));
        xmx = fmaxf(xmx, __shfl_xor(xmx, m));
        ymn = fminf(ymn, __shfl_xor(ymn, m));
        ymx = fmaxf(ymx, __shfl_xor(ymx, m));
    }
    if (k) return;
    if (e <= s) { wmask[n] = 0ull; return; }
    float wx = xmx - xmn, wy = ymx - ymn;
    float area = fmaxf(wx * wy, 1e-6f);
    float w = net_weights[n];
    const float INVB = 1.0f / 3.90625f;
    int j0 = (int)floorf(ymn * INVB);
    int j1 = (int)floorf(ymx * INVB);
    unsigned long long m = 0ull;
    if ((unsigned)j0 < 256u)       m |= 1ull << (j0 >> 2);
    if ((unsigned)(j0 + 1) < 256u) m |= 1ull << ((j0 + 1) >> 2);
    if ((unsigned)j1 < 256u)       m |= 1ull << (j1 >> 2);
    if ((unsigned)(j1 + 1) < 256u) m |= 1ull << ((j1 + 1) >> 2);
    wmask[n] = m;
    rec[2 * n]     = make_float4(ymn, ymx, xmn, xmx);
    rec[2 * n + 1] = make_float4(w * wx / area, w * wy / area, 0.f, 0.f);
}

// -- K2: prefetched filter + barrier-free append + single dense flush ----
__global__ __launch_bounds__(K2_THREADS) void accum11(
        const unsigned long long* __restrict__ wmask,
        const float4* __restrict__ rec,
        float* __restrict__ PT,          // [NCHUNK][2][NB(x)][NB(y)]
        int num_nets) {
    __shared__ float acc[2 * NW * NB];   // 8 KiB
    __shared__ int   l_idx[LCAP];        // 12 KiB
    __shared__ int   lcount;
    int* acci = (int*)acc;
    const int win   = blockIdx.x >> 3;   // 0..63
    const int chunk = blockIdx.x & 7;    // 0..7 == XCD id
    const int r0    = win * NW;
    const int tid   = threadIdx.x;
    const int lane  = tid & 63;
    const float BSX  = 3.90625f;
    const float INVB = 1.0f / 3.90625f;

    for (int i = tid; i < 2 * NW * NB; i += K2_THREADS) acci[i] = 0;
    if (tid == 0) lcount = 0;

    const int c0 = (int)((long long)num_nets * chunk / NCHUNK);
    const int c1 = (int)((long long)num_nets * (chunk + 1) / NCHUNK);
    const int nstrips = (c1 - c0 + K2_THREADS - 1) / K2_THREADS;

    // Prefetch all strips' wmask (independent loads -> one latency).
    unsigned long long wm[MAXSTRIPS];
    #pragma unroll
    for (int s = 0; s < MAXSTRIPS; ++s) {
        int n = c0 + s * K2_THREADS + tid;
        wm[s] = (s < nstrips && n < c1) ? wmask[n] : 0ull;
    }
    __syncthreads();   // acc zero-init visible; lcount=0 visible

    // Barrier-free append of all strips (order-independent downstream).
    for (int s = 0; s < nstrips; ++s) {
        int n = c0 + s * K2_THREADS + tid;
        bool hit = ((wm[s] >> win) & 1ull) != 0ull;
        unsigned long long m = __ballot(hit);
        if (m) {
            int base = 0;
            if (lane == 0) base = atomicAdd(&lcount, (int)__popcll(m));
            base = __shfl(base, 0);
            if (hit) {
                int pos = base + (int)__popcll(m & ((1ull << lane) - 1ull));
                if (pos < LCAP) l_idx[pos] = n;
            }
        }
    }
    __syncthreads();
    int cnt = lcount; if (cnt > LCAP) cnt = LCAP;

    // Plane-split dense flush: 2 threads per record (pl 0 = h, pl 1 = v).
    for (int ii = tid; ii < 2 * cnt; ii += K2_THREADS) {
        int i  = (ii < cnt) ? ii : ii - cnt;
        int pl = (ii < cnt) ? 0 : 1;
        int n = l_idx[i];
        float4 a = rec[2 * n];       // one 32B line per record
        float4 b = rec[2 * n + 1];
        float ty0 = a.x * INVB, fj0 = floorf(ty0);
        float ty1 = a.y * INVB, fj1 = floorf(ty1);
        int j0 = (int)fj0, j1 = (int)fj1;
        float f0 = ty0 - fj0, f1 = ty1 - fj1;
        float tx0 = a.z * INVB, g0 = floorf(tx0);
        float tx1 = a.w * INVB, g1 = floorf(tx1);
        int i0 = (int)g0, i1 = (int)g1;
        float h0 = tx0 - g0, h1 = tx1 - g1;
        float d = pl ? b.y : b.x;
        int* bp = acci + pl * (NW * NB);
        int   xx[4] = { i0, i0 + 1, i1, i1 + 1 };
        float ax[4] = { BSX * (1.f - h0), BSX * h0,
                       -BSX * (1.f - h1), -BSX * h1 };
        int   rr[4] = { j0, j0 + 1, j1, j1 + 1 };
        float rw[4] = { BSX * (1.f - f0), BSX * f0,
                       -BSX * (1.f - f1), -BSX * f1 };
        #pragma unroll
        for (int q = 0; q < 4; ++q) {
            int ro = rr[q] - r0;
            if ((unsigned)ro >= NW) continue;
            float wd = rw[q] * d * FXS;
            int* b2 = bp + ro * NB;
            #pragma unroll
            for (int p = 0; p < 4; ++p) {
                int x = xx[p];
                if (x >= NB) continue;
                atomicAdd(b2 + x, __float2int_rn(ax[p] * wd));
            }
        }
    }
    __syncthreads();

    // x-cumsum (convert fixed->float in-place): one wave per row (8 rows).
    const int wave = tid >> 6;
    for (int row = wave; row < 2 * NW; row += (K2_THREADS / 64)) {
        float carry = 0.f;
        #pragma unroll
        for (int seg = 0; seg < NB / 64; ++seg) {
            int idx = row * NB + seg * 64 + lane;
            float v = (float)acci[idx] * INV_FXS;
            #pragma unroll
            for (int off = 1; off < 64; off <<= 1) {
                float u = __shfl_up(v, off);
                if (lane >= off) v += u;
            }
            v += carry;
            acc[idx] = v;
            carry = __shfl(v, 63);
        }
    }
    __syncthreads();

    // Transposed store: PT[chunk][plane][x][r0..r0+4) = one float4 per (p,x).
    if (tid < 512) {
        int p = tid >> 8;
        int x = tid & 255;
        int base = p * NW * NB;
        float4 v;
        v.x = acc[base + 0 * NB + x];
        v.y = acc[base + 1 * NB + x];
        v.z = acc[base + 2 * NB + x];
        v.w = acc[base + 3 * NB + x];
        float* dst = PT + ((((long long)chunk * 2 + p) * NB + x) * NB) + r0;
        *(float4*)dst = v;
    }
}

// ---------------- K3: chunk-sum + y-cumsum + util (all coalesced) --------
__global__ __launch_bounds__(512) void yscan_util(
        const float* __restrict__ PT, float* __restrict__ utilT) {
    __shared__ float buf[2 * NB];
    const int x = blockIdx.x;
    const int plane = threadIdx.x >> 8;
    const int y = threadIdx.x & (NB - 1);
    float s = 0.f;
    #pragma unroll
    for (int c = 0; c < NCHUNK; ++c)
        s += PT[(((long long)c * 2 + plane) * NB + x) * NB + y];
    float* b = buf + plane * NB;
    b[y] = s;
    #pragma unroll
    for (int off = 1; off < NB; off <<= 1) {
        __syncthreads();
        float a = (y >= off) ? b[y - off] : 0.0f;
        __syncthreads();
        b[y] += a;
    }
    __syncthreads();
    if (plane == 0) {
        const float INV_CH = 1.0f / (3.90625f * 3.90625f * 1.5625f);
        const float INV_CV = 1.0f / (3.90625f * 3.90625f * 1.45f);
        float u = fmaxf(buf[y] * INV_CH, buf[NB + y] * INV_CV);
        u = fminf(fmaxf(u, 0.5f), 2.0f);
        utilT[x * NB + y] = u;
    }
}

// ---------------- K4: per-instance area (util transposed [x][y]) --------
__global__ void instance_area(const float* __restrict__ pos,
                              const float* __restrict__ nsx,
                              const float* __restrict__ nsy,
                              const float* __restrict__ utilT,
                              float* __restrict__ out,
                              int num_movable, int num_nodes) {
    int i = blockIdx.x * blockDim.x + threadIdx.x;
    if (i >= num_movable) return;
    const float BSX = 3.90625f;
    const float INVB = 1.0f / 3.90625f;
    float x0f = pos[i];
    float y0f = pos[num_nodes + i];
    float x1f = x0f + nsx[i];
    float y1f = y0f + nsy[i];
    int kx0 = max(0, min(NB - 1, (int)floorf(x0f * INVB)));
    int kx1 = max(0, min(NB - 1, (int)floorf(x1f * INVB)));
    int ky0 = max(0, min(NB - 1, (int)floorf(y0f * INVB)));
    int ky1 = max(0, min(NB - 1, (int)floorf(y1f * INVB)));
    float acc = 0.0f;
    for (int kx = kx0; kx <= kx1; ++kx) {
        float bx = kx * BSX;
        float ovx = fmaxf(fminf(x1f, bx + BSX) - fmaxf(x0f, bx), 0.0f);
        const float* ucol = utilT + kx * NB;
        float accy = 0.0f;
        for (int ky = ky0; ky <= ky1; ++ky) {
            float by = ky * BSX;
            float ovy = fmaxf(fminf(y1f, by + BSX) - fmaxf(y0f, by), 0.0f);
            accy += ovy * ucol[ky];
        }
        acc += accy * ovx;
    }
    out[i] = acc;
}

// ---------------- fallback (tiny workspace): round-1 style ----------------
__global__ void fb_zero(float* g, int n) {
    int i = blockIdx.x * blockDim.x + threadIdx.x;
    int stride = gridDim.x * blockDim.x;
    for (; i < n; i += stride) g[i] = 0.0f;
}

__global__ void fb_scatter(const float* __restrict__ pin_pos,
                           const float* __restrict__ net_weights,
                           const void* __restrict__ netpin_start,
                           const void* __restrict__ flat_netpin,
                           float* __restrict__ G2,
                           int num_nets, int num_pins) {
    int n = blockIdx.x * blockDim.x + threadIdx.x;
    if (n >= num_nets) return;
    const int is64 = (((const int*)netpin_start)[1] == 0);
    long long s = load_idx(netpin_start, n, is64);
    long long e = load_idx(netpin_start, n + 1, is64);
    if (e <= s) return;
    float xmn = 3e38f, xmx = -3e38f, ymn = 3e38f, ymx = -3e38f;
    for (long long p = s; p < e; ++p) {
        long long pin = load_idx(flat_netpin, p, is64);
        float px = pin_pos[pin], py = pin_pos[pin + num_pins];
        xmn = fminf(xmn, px); xmx = fmaxf(xmx, px);
        ymn = fminf(ymn, py); ymx = fmaxf(ymx, py);
    }
    float wx = xmx - xmn, wy = ymx - ymn;
    float area = fmaxf(wx * wy, 1e-6f);
    float w = net_weights[n];
    float dh = w * wx / area, dv = w * wy / area;
    const float BSX = 3.90625f, INVB = 1.0f / 3.90625f;
    int jx[4]; float ax[4]; int jy[4]; float ay[4];
    float t, fj, f; int j;
    t = xmn * INVB; fj = floorf(t); j = (int)fj; f = t - fj;
    jx[0] = j; ax[0] = BSX * (1.f - f); jx[1] = j + 1; ax[1] = BSX * f;
    t = xmx * INVB; fj = floorf(t); j = (int)fj; f = t - fj;
    jx[2] = j; ax[2] = -BSX * (1.f - f); jx[3] = j + 1; ax[3] = -BSX * f;
    t = ymn * INVB; fj = floorf(t); j = (int)fj; f = t - fj;
    jy[0] = j; ay[0] = BSX * (1.f - f); jy[1] = j + 1; ay[1] = BSX * f;
    t = ymx * INVB; fj = floorf(t); j = (int)fj; f = t - fj;
    jy[2] = j; ay[2] = -BSX * (1.f - f); jy[3] = j + 1; ay[3] = -BSX * f;
    #pragma unroll
    for (int b = 0; b < 4; ++b) {
        int y = jy[b];
        if (y < 0 || y >= NB) continue;
        #pragma unroll
        for (int a2 = 0; a2 < 4; ++a2) {
            int x = jx[a2];
            if (x < 0 || x >= NB) continue;
            float g = ax[a2] * ay[b];
            atomicAdd(&G2[(y * NB + x) * 2],     dh * g);
            atomicAdd(&G2[(y * NB + x) * 2 + 1], dv * g);
        }
    }
}

__global__ void fb_rowscan(float2* G2) {
    int y = blockIdx.x, t = threadIdx.x;
    __shared__ float sh[NB]; __shared__ float sv[NB];
    float2 v = G2[y * NB + t];
    sh[t] = v.x; sv[t] = v.y;
    #pragma unroll
    for (int off = 1; off < NB; off <<= 1) {
        __syncthreads();
        float a = (t >= off) ? sh[t - off] : 0.0f;
        float b = (t >= off) ? sv[t - off] : 0.0f;
        __syncthreads();
        sh[t] += a; sv[t] += b;
    }
    __syncthreads();
    G2[y * NB + t] = make_float2(sh[t], sv[t]);
}

__global__ void fb_colscan(const float2* __restrict__ G2, float* __restrict__ utilT) {
    int x = blockIdx.x, t = threadIdx.x;
    const float INV_CH = 1.0f / (3.90625f * 3.90625f * 1.5625f);
    const float INV_CV = 1.0f / (3.90625f * 3.90625f * 1.45f);
    __shared__ float sh[NB]; __shared__ float sv[NB];
    float2 g = G2[t * NB + x];
    sh[t] = g.x; sv[t] = g.y;
    #pragma unroll
    for (int off = 1; off < NB; off <<= 1) {
        __syncthreads();
        float a = (t >= off) ? sh[t - off] : 0.0f;
        float b = (t >= off) ? sv[t - off] : 0.0f;
        __syncthreads();
        sh[t] += a; sv[t] += b;
    }
    __syncthreads();
    float u = fmaxf(sh[t] * INV_CH, sv[t] * INV_CV);
    utilT[x * NB + t] = fminf(fmaxf(u, 0.5f), 2.0f);
}

extern "C" void kernel_launch(void* const* d_in, const int* in_sizes, int n_in,
                              void* d_out, int out_size, void* d_ws, size_t ws_size,
                              hipStream_t stream) {
    const float* pos          = (const float*)d_in[0];
    const float* pin_pos      = (const float*)d_in[1];
    const float* nsx          = (const float*)d_in[2];
    const float* nsy          = (const float*)d_in[3];
    const float* net_weights  = (const float*)d_in[4];
    const void*  netpin_start = d_in[5];
    const void*  flat_netpin  = d_in[6];
    float* out = (float*)d_out;

    int num_pins    = in_sizes[1] / 2;
    int num_nodes   = in_sizes[2];
    int num_nets    = in_sizes[4];
    int num_movable = out_size;

    // ws (floats): wmask_u64[n] (2n) | rec[8n] | PT[8*2*NB*NB] | utilT[NB*NB]
    auto align4 = [](size_t v) { return (v + 3) & ~(size_t)3; };
    size_t mk_off  = 0;
    size_t rec_off = align4(mk_off + 2LL * num_nets);
    size_t PT_off  = align4(rec_off + 8LL * num_nets);
    size_t PT_f    = (size_t)NCHUNK * 2 * NB * NB;
    size_t ut_off  = PT_off + PT_f;
    size_t need    = (ut_off + (size_t)NB * NB) * sizeof(float);

    bool strips_ok = ((num_nets + NCHUNK - 1) / NCHUNK + K2_THREADS - 1) / K2_THREADS
                     <= MAXSTRIPS;

    if (ws_size >= need && strips_ok) {
        float* base = (float*)d_ws;
        unsigned long long* wmask = (unsigned long long*)(base + mk_off);
        float4* rec = (float4*)(base + rec_off);
        float*  PT  = base + PT_off;
        float*  ut  = base + ut_off;

        int g1 = (4 * num_nets + 255) / 256;
        bbox_kernel<<<g1, 256, 0, stream>>>(pin_pos, net_weights, netpin_start,
                                            flat_netpin, wmask, rec,
                                            num_nets, num_pins);
        accum11<<<NWIN * NCHUNK, K2_THREADS, 0, stream>>>(wmask, rec, PT, num_nets);
        yscan_util<<<NB, 512, 0, stream>>>(PT, ut);
        int gi = (num_movable + 255) / 256;
        instance_area<<<gi, 256, 0, stream>>>(pos, nsx, nsy, ut, out,
                                              num_movable, num_nodes);
        return;
    }

    // -------- fallback: round-1 style (768KB workspace) --------
    {
        float* G2   = (float*)d_ws;
        float* util = G2 + NB * NB * 2;    // utilT [x][y]
        fb_zero<<<256, 256, 0, stream>>>(G2, NB * NB * 2);
        int gn = (num_nets + 255) / 256;
        fb_scatter<<<gn, 256, 0, stream>>>(pin_pos, net_weights, netpin_start,
                                           flat_netpin, G2, num_nets, num_pins);
        fb_rowscan<<<NB, 256, 0, stream>>>((float2*)G2);
        fb_colscan<<<NB, 256, 0, stream>>>((const float2*)G2, util);
        int gi = (num_movable + 255) / 256;
        instance_area<<<gi, 256, 0, stream>>>(pos, nsx, nsy, util, out,
                                              num_movable, num_nodes);
    }
}